// Round 7
// baseline (188.687 us; speedup 1.0000x reference)
//
#include <hip/hip_runtime.h>
#include <hip/hip_bf16.h>

typedef __attribute__((ext_vector_type(8))) short bf16x8;
typedef __attribute__((ext_vector_type(16))) float f32x16;
typedef __attribute__((ext_vector_type(4))) unsigned short ushort4v;

static __device__ __forceinline__ unsigned short f2bf(float f) {
  unsigned u = __float_as_uint(f);
  return (unsigned short)((u + 0x7FFFu + ((u >> 16) & 1u)) >> 16);
}
static __device__ __forceinline__ float silu_f(float v) { return v / (1.f + __expf(-v)); }

#define MFMA32(a, b, c) __builtin_amdgcn_mfma_f32_32x32x16_bf16((a), (b), (c), 0, 0, 0)

// ---- K0: fused weight pack (A-fragment order) + 4x4 avg pool ----
// A-frag pack: lane l holds row rb*32+(l&31), k = ks*16 + (l>>5)*8 + i.
// packed[((rb*NKS+ks)*64 + l)*8 + i]
__global__ void prep_k(const float* __restrict__ shw, const float* __restrict__ ew1,
                       const float* __restrict__ ew2, const float* __restrict__ x,
                       unsigned short* __restrict__ wshp, unsigned short* __restrict__ w1p,
                       unsigned short* __restrict__ w2p, float* __restrict__ xp) {
  const int bid = blockIdx.x;
  if (bid < 4352) {
    int idx = bid * 256 + threadIdx.x;
    if (idx < 65536) {  // shared_w [256,256], NKS=16
      int j = idx;
      int i = j & 7, l = (j >> 3) & 63, ks = (j >> 9) & 15, rb = j >> 13;
      int row = rb * 32 + (l & 31), k = ks * 16 + (l >> 5) * 8 + i;
      wshp[j] = f2bf(shw[row * 256 + k]);
    } else if (idx < 589824) {  // expert_w1 [4,512,256], NKS=16
      int j = idx - 65536;
      int i = j & 7, l = (j >> 3) & 63, ks = (j >> 9) & 15, rb = (j >> 13) & 15, e = j >> 17;
      int row = rb * 32 + (l & 31), k = ks * 16 + (l >> 5) * 8 + i;
      w1p[j] = f2bf(ew1[((size_t)e * 512 + row) * 256 + k]);
    } else if (idx < 1114112) {  // expert_w2 [4,256,512], NKS=32
      int j = idx - 589824;
      int i = j & 7, l = (j >> 3) & 63, ks = (j >> 9) & 31, rb = (j >> 14) & 7, e = j >> 17;
      int row = rb * 32 + (l & 31), k = ks * 16 + (l >> 5) * 8 + i;
      w2p[j] = f2bf(ew2[((size_t)e * 256 + row) * 512 + k]);
    }
  } else {
    int idx = (bid - 4352) * 256 + threadIdx.x;
    if (idx >= 16 * 256 * 196) return;
    int pj = idx % 14, tmp = idx / 14, pi = tmp % 14, bc = tmp / 14;
    const float* src = x + (size_t)bc * 3136 + pi * 4 * 56 + pj * 4;
    float s = 0.f;
#pragma unroll
    for (int u = 0; u < 4; ++u) {
      float4 v = *reinterpret_cast<const float4*>(src + u * 56);
      s += v.x + v.y + v.z + v.w;
    }
    xp[idx] = s * 0.0625f;
  }
}

// ---- K2: router 3x3 conv + SiLU + spatial sum. block=(b,r), 512 blocks. ----
// Wave w owns channels {cc*32 + w*8 .. +8} per chunk (64 c total). 49 lanes
// each compute a 2x2 pixel block in registers: 16 x-reads + 9 broadcast
// w-reads per 36 MACs. Cross-wave combine -> silu -> spatial sum.
__global__ __launch_bounds__(256) void router_conv_k(const float* __restrict__ xp,
                                                     const float* __restrict__ rw1,
                                                     float* __restrict__ hsum) {
  const int b = blockIdx.x >> 5, r = blockIdx.x & 31;
  __shared__ float wl[2304];
  __shared__ float xl[32][256];  // 32 channels, padded 16x16 planes
  __shared__ float red[4][196];
  __shared__ float red2[4];
  const int t = threadIdx.x;
  const int w = t >> 6, l = t & 63;
  for (int i = t; i < 2304; i += 256) wl[i] = rw1[r * 2304 + i];
  for (int i = t; i < 32 * 256; i += 256) (&xl[0][0])[i] = 0.f;  // borders stay zero
  const int ui = (l < 49) ? (l / 7) : 0, uj = (l < 49) ? (l % 7) : 0;
  float acc[4] = {0.f, 0.f, 0.f, 0.f};
  for (int cc = 0; cc < 8; ++cc) {
    __syncthreads();
    for (int i = t; i < 32 * 196; i += 256) {
      int c = i / 196, px = i % 196;
      xl[c][(px / 14 + 1) * 16 + (px % 14 + 1)] =
          xp[((size_t)b * 256 + cc * 32 + c) * 196 + px];
    }
    __syncthreads();
    if (l < 49) {
#pragma unroll 2
      for (int ci = 0; ci < 8; ++ci) {
        const int c = w * 8 + ci;
        float xv[4][4];
        const float* xb = &xl[c][ui * 32 + uj * 2];
#pragma unroll
        for (int dr = 0; dr < 4; ++dr)
#pragma unroll
          for (int dc = 0; dc < 4; ++dc) xv[dr][dc] = xb[dr * 16 + dc];
        const float* wp = &wl[(cc * 32 + c) * 9];
        float wv[9];
#pragma unroll
        for (int j = 0; j < 9; ++j) wv[j] = wp[j];  // uniform addr -> broadcast
#pragma unroll
        for (int di = 0; di < 2; ++di)
#pragma unroll
          for (int dj = 0; dj < 2; ++dj) {
            float a = acc[di * 2 + dj];
#pragma unroll
            for (int du = 0; du < 3; ++du)
#pragma unroll
              for (int dv = 0; dv < 3; ++dv)
                a += xv[di + du][dj + dv] * wv[du * 3 + dv];
            acc[di * 2 + dj] = a;
          }
      }
    }
  }
  if (l < 49) {
#pragma unroll
    for (int k = 0; k < 4; ++k) red[w][(ui * 7 + uj) * 4 + k] = acc[k];
  }
  __syncthreads();
  float s = 0.f;
  if (t < 196) {
    float tot = red[0][t] + red[1][t] + red[2][t] + red[3][t];
    s = silu_f(tot);
  }
#pragma unroll
  for (int off = 32; off > 0; off >>= 1) s += __shfl_down(s, off);
  if ((t & 63) == 0) red2[t >> 6] = s;
  __syncthreads();
  if (t == 0) hsum[b * 32 + r] = red2[0] + red2[1] + red2[2] + red2[3];
}

// ---- K3: logits -> softmax -> top-2 -> normalized weights ----
__global__ void topk_k(const float* __restrict__ hsum, const float* __restrict__ rw2,
                       float* __restrict__ selv, int* __restrict__ sele) {
  const int t = threadIdx.x;
  const int b = t >> 2, e = t & 3;
  float l = 0.f;
#pragma unroll
  for (int r = 0; r < 32; ++r) l += rw2[e * 32 + r] * hsum[b * 32 + r];
  l *= (1.f / 196.f);
  float m = fmaxf(l, __shfl_xor(l, 1));
  m = fmaxf(m, __shfl_xor(m, 2));
  float p = __expf(l - m);
  float sm = p + __shfl_xor(p, 1);
  sm += __shfl_xor(sm, 2);
  float prob = p / sm;
  float p0 = __shfl(prob, (b << 2) | 0);
  float p1 = __shfl(prob, (b << 2) | 1);
  float p2 = __shfl(prob, (b << 2) | 2);
  float p3 = __shfl(prob, (b << 2) | 3);
  if (e == 0) {
    float pr[4] = {p0, p1, p2, p3};
    int i1 = 0;
    for (int i = 1; i < 4; ++i)
      if (pr[i] > pr[i1]) i1 = i;
    int i2 = (i1 == 0) ? 1 : 0;
    for (int i = 0; i < 4; ++i) {
      if (i == i1 || i == i2) continue;
      if (pr[i] > pr[i2]) i2 = i;
    }
    float denom = pr[i1] + pr[i2] + 1e-6f;
    selv[b * 2 + 0] = pr[i1] / denom;
    selv[b * 2 + 1] = pr[i2] / denom;
    sele[b * 2 + 0] = i1;
    sele[b * 2 + 1] = i2;
  }
}

// rf=2 GEMM (tail stage2): 2 row-blocks x 2 px-blocks, NKS k-steps.
template <int NKS>
static __device__ __forceinline__ void gemm_rf2(
    const unsigned short* __restrict__ A0, const unsigned short* __restrict__ A1,
    const unsigned short* B0, const unsigned short* B1, f32x16 acc[2][2]) {
#pragma unroll
  for (int kk = 0; kk < NKS; ++kk) {
    const bf16x8 a0 = *reinterpret_cast<const bf16x8*>(A0 + kk * 512);
    const bf16x8 a1 = *reinterpret_cast<const bf16x8*>(A1 + kk * 512);
    const bf16x8 b0 = *reinterpret_cast<const bf16x8*>(B0 + kk * 1024);
    const bf16x8 b1 = *reinterpret_cast<const bf16x8*>(B1 + kk * 1024);
    acc[0][0] = MFMA32(a0, b0, acc[0][0]);
    acc[0][1] = MFMA32(a0, b1, acc[0][1]);
    acc[1][0] = MFMA32(a1, b0, acc[1][0]);
    acc[1][1] = MFMA32(a1, b1, acc[1][1]);
  }
}

// ---- K4: fused MoE main. 4 waves x 64px. Cross-phase dual-GEMM interleave:
// stage1(phase p) overlaps stage2(phase p-1) in one loop (independent chains).
// Phases = 128 hidden rows; hs double-buffered. One barrier per iteration.
// xs: [kgroup 0..31][px 0..63][8] (32 KB). hs: [2][16][64][8] (32 KB).
__global__ __launch_bounds__(256, 2) void moe_main_k(
    const float* __restrict__ x, const unsigned short* __restrict__ wshp,
    const unsigned short* __restrict__ w1p, const unsigned short* __restrict__ w2p,
    const float* __restrict__ selv, const int* __restrict__ sele,
    float* __restrict__ out) {
  constexpr int HW = 3136;
  __shared__ __align__(16) unsigned short xs[32 * 64 * 8];      // 32 KB
  __shared__ __align__(16) unsigned short hs[2][16 * 64 * 8];   // 32 KB

  const int b = blockIdx.x / 49, tile = blockIdx.x - b * 49;
  const int px0 = tile * 64;
  const int t = threadIdx.x;
  const int w = t >> 6, l = t & 63;
  const int l31 = l & 31, lh = l >> 5;

  // ---- stage x tile: thread handles px=l, channels w*64+cg*8+i ----
  {
    const float* xb = x + (size_t)b * 256 * HW + px0 + l;
#pragma unroll
    for (int cg = 0; cg < 8; ++cg) {
      const int c0 = w * 64 + cg * 8;
      alignas(16) unsigned short tmp[8];
#pragma unroll
      for (int i = 0; i < 8; ++i) tmp[i] = f2bf(xb[(size_t)(c0 + i) * HW]);
      *reinterpret_cast<bf16x8*>(&xs[((c0 >> 3) * 64 + l) * 8]) =
          *reinterpret_cast<const bf16x8*>(tmp);
    }
  }

  const unsigned short* xB0 = xs + (lh * 64 + l31) * 8;
  const unsigned short* xB1 = xB0 + 256;

  const int e0 = sele[b * 2 + 0], e1 = sele[b * 2 + 1];
  const float v0 = selv[b * 2 + 0], v1 = selv[b * 2 + 1];

  f32x16 oacc[2][2];
  f32x16 hacc[2];
#pragma unroll
  for (int i = 0; i < 2; ++i)
#pragma unroll
    for (int j = 0; j < 2; ++j)
#pragma unroll
      for (int r = 0; r < 16; ++r) oacc[i][j][r] = 0.f;
#pragma unroll
  for (int j = 0; j < 2; ++j)
#pragma unroll
    for (int r = 0; r < 16; ++r) hacc[j][r] = 0.f;

  __syncthreads();

  // ---- iteration 0: shared expert (rf2, K=256) || stage1 phase0 (e0, ch0) ----
  {
    const unsigned short* A1 = w1p + (size_t)((e0 * 16 + w) * 16) * 512 + l * 8;
    const unsigned short* As = wshp + (size_t)(w * 2) * 16 * 512 + l * 8;
#pragma unroll
    for (int kk = 0; kk < 16; ++kk) {
      const bf16x8 a1 = *reinterpret_cast<const bf16x8*>(A1 + kk * 512);
      const bf16x8 s0 = *reinterpret_cast<const bf16x8*>(As + kk * 512);
      const bf16x8 s1 = *reinterpret_cast<const bf16x8*>(As + 8192 + kk * 512);
      const bf16x8 b0 = *reinterpret_cast<const bf16x8*>(xB0 + kk * 1024);
      const bf16x8 b1 = *reinterpret_cast<const bf16x8*>(xB1 + kk * 1024);
      hacc[0] = MFMA32(a1, b0, hacc[0]);
      hacc[1] = MFMA32(a1, b1, hacc[1]);
      oacc[0][0] = MFMA32(s0, b0, oacc[0][0]);
      oacc[0][1] = MFMA32(s0, b1, oacc[0][1]);
      oacc[1][0] = MFMA32(s1, b0, oacc[1][0]);
      oacc[1][1] = MFMA32(s1, b1, oacc[1][1]);
    }
  }
#pragma unroll
  for (int i = 0; i < 2; ++i)
#pragma unroll
    for (int j = 0; j < 2; ++j)
#pragma unroll
      for (int r = 0; r < 16; ++r) oacc[i][j][r] = silu_f(oacc[i][j][r]);

  // write hs[0] = v0 * silu(hacc)   (no preceding barrier needed: first use)
#pragma unroll
  for (int cf = 0; cf < 2; ++cf)
#pragma unroll
    for (int g = 0; g < 4; ++g) {
      alignas(8) unsigned short pk[4];
#pragma unroll
      for (int j = 0; j < 4; ++j) pk[j] = f2bf(v0 * silu_f(hacc[cf][g * 4 + j]));
      const int ui2 = ((w * 4 + g) * 64 + cf * 32 + l31) * 8 + lh * 4;
      *reinterpret_cast<ushort4v*>(&hs[0][ui2]) = *reinterpret_cast<const ushort4v*>(pk);
    }
  __syncthreads();

  // ---- iterations 1..7: stage1(p) || stage2(p-1) ----
#pragma unroll 1
  for (int p = 1; p < 8; ++p) {
    const int e = (p >> 2) ? e1 : e0, ch = p & 3;
    const int ep = ((p - 1) >> 2) ? e1 : e0, chp = (p - 1) & 3;
    const float v = (p >> 2) ? v1 : v0;
    const unsigned short* A1 = w1p + (size_t)((e * 16 + ch * 4 + w) * 16) * 512 + l * 8;
    const unsigned short* A2 = w2p + ((size_t)(ep * 8 + w * 2) * 32 + chp * 8) * 512 + l * 8;
    const unsigned short* B2 = hs[(p - 1) & 1] + (lh * 64 + l31) * 8;
#pragma unroll
    for (int j = 0; j < 2; ++j)
#pragma unroll
      for (int r = 0; r < 16; ++r) hacc[j][r] = 0.f;
#pragma unroll
    for (int kk = 0; kk < 16; ++kk) {
      const bf16x8 a1 = *reinterpret_cast<const bf16x8*>(A1 + kk * 512);
      const bf16x8 b0 = *reinterpret_cast<const bf16x8*>(xB0 + kk * 1024);
      const bf16x8 b1 = *reinterpret_cast<const bf16x8*>(xB1 + kk * 1024);
      hacc[0] = MFMA32(a1, b0, hacc[0]);
      hacc[1] = MFMA32(a1, b1, hacc[1]);
      if ((kk & 1) == 0) {
        const int ks2 = kk >> 1;
        const bf16x8 a20 = *reinterpret_cast<const bf16x8*>(A2 + ks2 * 512);
        const bf16x8 a21 = *reinterpret_cast<const bf16x8*>(A2 + 16384 + ks2 * 512);
        const bf16x8 h0 = *reinterpret_cast<const bf16x8*>(B2 + ks2 * 1024);
        const bf16x8 h1 = *reinterpret_cast<const bf16x8*>(B2 + 256 + ks2 * 1024);
        oacc[0][0] = MFMA32(a20, h0, oacc[0][0]);
        oacc[0][1] = MFMA32(a20, h1, oacc[0][1]);
        oacc[1][0] = MFMA32(a21, h0, oacc[1][0]);
        oacc[1][1] = MFMA32(a21, h1, oacc[1][1]);
      }
    }
    // write hs[p&1] = v * silu(hacc). Safe without extra barrier: readers of
    // hs[p&1] (stage2 of p-2, in iteration p-1) are ordered by the previous
    // iteration's post-write barrier.
#pragma unroll
    for (int cf = 0; cf < 2; ++cf)
#pragma unroll
      for (int g = 0; g < 4; ++g) {
        alignas(8) unsigned short pk[4];
#pragma unroll
        for (int j = 0; j < 4; ++j) pk[j] = f2bf(v * silu_f(hacc[cf][g * 4 + j]));
        const int ui2 = ((w * 4 + g) * 64 + cf * 32 + l31) * 8 + lh * 4;
        *reinterpret_cast<ushort4v*>(&hs[p & 1][ui2]) =
            *reinterpret_cast<const ushort4v*>(pk);
      }
    __syncthreads();
  }

  // ---- tail: stage2 of phase 7 (e1, ch=3), hs[1] ----
  {
    const unsigned short* A2 = w2p + ((size_t)(e1 * 8 + w * 2) * 32 + 3 * 8) * 512 + l * 8;
    const unsigned short* B2 = hs[1] + (lh * 64 + l31) * 8;
    gemm_rf2<8>(A2, A2 + 16384, B2, B2 + 256, oacc);
  }

  // ---- write out[b, o, px] ----
#pragma unroll
  for (int rfi = 0; rfi < 2; ++rfi)
#pragma unroll
    for (int cf = 0; cf < 2; ++cf)
#pragma unroll
      for (int r = 0; r < 16; ++r) {
        const int o = w * 64 + rfi * 32 + (r & 3) + 8 * (r >> 2) + 4 * lh;
        out[((size_t)b * 256 + o) * HW + px0 + cf * 32 + l31] = oacc[rfi][cf][r];
      }
}

extern "C" void kernel_launch(void* const* d_in, const int* in_sizes, int n_in,
                              void* d_out, int out_size, void* d_ws, size_t ws_size,
                              hipStream_t stream) {
  const float* x = (const float*)d_in[0];
  const float* rw1 = (const float*)d_in[1];
  const float* rw2 = (const float*)d_in[2];
  const float* ew1 = (const float*)d_in[3];
  const float* ew2 = (const float*)d_in[4];
  const float* shw = (const float*)d_in[5];
  float* out = (float*)d_out;
  char* ws = (char*)d_ws;

  float* xp = (float*)(ws);                                // 3,211,264 B
  float* hsum = (float*)(ws + 3211264);
  float* selv = (float*)(ws + 3213312);
  int* sele = (int*)(ws + 3213440);
  unsigned short* wshp = (unsigned short*)(ws + 3213568);  // 128 KB
  unsigned short* w1p = wshp + 65536;                      // 1 MB
  unsigned short* w2p = w1p + 524288;                      // 1 MB

  prep_k<<<7488, 256, 0, stream>>>(shw, ew1, ew2, x, wshp, w1p, w2p, xp);
  router_conv_k<<<512, 256, 0, stream>>>(xp, rw1, hsum);
  topk_k<<<1, 64, 0, stream>>>(hsum, rw2, selv, sele);
  moe_main_k<<<784, 256, 0, stream>>>(x, wshp, w1p, w2p, selv, sele, out);
}